// Round 1
// baseline (1078.071 us; speedup 1.0000x reference)
//
#include <hip/hip_runtime.h>
#include <math.h>

// Polarisation: Thole-damped dipole field + diagonal 1/alpha term.
// out[n] = mu[n]/pol[n] + sum_{e: src=n} [ lam3/r^3 * mu[dst] - 3*lam5/r^5 * (vec.mu[dst]) * vec ]
// (all in Bohr units; inputs in Angstrom)

#define INV_BOHR   1.8897261254578281f   // 1 / 0.52917721067
#define INV_BOHR3  (INV_BOHR*INV_BOHR*INV_BOHR)
#define A_MUTUAL   0.39f

// Kernel A: per-node. out = mu / pol_bohr ; q = pol_bohr^(-1/6)
__global__ void pol_node_kernel(const float* __restrict__ pol_ang,
                                const float* __restrict__ mu,
                                float* __restrict__ out,
                                float* __restrict__ q,
                                int n_nodes) {
    int i = blockIdx.x * blockDim.x + threadIdx.x;
    if (i >= n_nodes) return;
    float pol = pol_ang[i] * INV_BOHR3;      // polarisability in bohr^3
    float ip  = 1.0f / pol;
    out[3*i + 0] = mu[3*i + 0] * ip;
    out[3*i + 1] = mu[3*i + 1] * ip;
    out[3*i + 2] = mu[3*i + 2] * ip;
    q[i] = powf(pol, -1.0f / 6.0f);          // so u_ij = r * q[s] * q[d]
}

// Kernel B: per-edge scatter-add of the Thole-damped interaction into out[src].
__global__ void pol_edge_kernel(const int*   __restrict__ src,
                                const int*   __restrict__ dst,
                                const float* __restrict__ dist,
                                const float* __restrict__ vec,
                                const float* __restrict__ q,
                                const float* __restrict__ mu,
                                float* __restrict__ out,
                                int n_edges) {
    int e = blockIdx.x * blockDim.x + threadIdx.x;
    if (e >= n_edges) return;

    int s = src[e];
    int d = dst[e];

    float rij = dist[e] * INV_BOHR;
    float u   = rij * q[s] * q[d];
    float au3 = A_MUTUAL * u * u * u;

    // expm1-based: cancellation-free lam3/lam5.
    // em1 = exp(-au3) - 1 ; lam3 = 1-exp = -em1 ; lam5 = 1-(1+au3)exp = -(em1 + au3*(em1+1))
    float em1  = expm1f(-au3);
    float lam3 = -em1;
    float lam5 = -(em1 + au3 * (em1 + 1.0f));

    float inv_r  = 1.0f / rij;
    float inv_r2 = inv_r * inv_r;
    float inv_r3 = inv_r2 * inv_r;
    float inv_r5 = inv_r3 * inv_r2;

    float vx = vec[3*e + 0] * INV_BOHR;
    float vy = vec[3*e + 1] * INV_BOHR;
    float vz = vec[3*e + 2] * INV_BOHR;

    float mx = mu[3*d + 0];
    float my = mu[3*d + 1];
    float mz = mu[3*d + 2];

    float dot = vx*mx + vy*my + vz*mz;

    float c3 = lam3 * inv_r3;
    float c5 = 3.0f * lam5 * inv_r5 * dot;

    atomicAdd(&out[3*s + 0], c3*mx - c5*vx);
    atomicAdd(&out[3*s + 1], c3*my - c5*vy);
    atomicAdd(&out[3*s + 2], c3*mz - c5*vz);
}

extern "C" void kernel_launch(void* const* d_in, const int* in_sizes, int n_in,
                              void* d_out, int out_size, void* d_ws, size_t ws_size,
                              hipStream_t stream) {
    // setup_inputs order:
    // 0: species (int, unused)
    // 1: edge_src (int)   2: edge_dst (int)
    // 3: distances (f32)  4: vec (f32, [E,3])
    // 5: polarisability (f32, [N])  6: mu (f32, [N,3])
    const int*   edge_src = (const int*)d_in[1];
    const int*   edge_dst = (const int*)d_in[2];
    const float* dist     = (const float*)d_in[3];
    const float* vec      = (const float*)d_in[4];
    const float* pol      = (const float*)d_in[5];
    const float* mu       = (const float*)d_in[6];

    float* out = (float*)d_out;          // [N,3] f32
    float* q   = (float*)d_ws;           // [N] f32 scratch: pol^(-1/6)

    int n_nodes = in_sizes[5];
    int n_edges = in_sizes[1];

    pol_node_kernel<<<(n_nodes + 255) / 256, 256, 0, stream>>>(pol, mu, out, q, n_nodes);
    pol_edge_kernel<<<(n_edges + 255) / 256, 256, 0, stream>>>(edge_src, edge_dst, dist, vec,
                                                               q, mu, out, n_edges);
}